// Round 3
// baseline (1170.830 us; speedup 1.0000x reference)
//
#include <hip/hip_runtime.h>

// ---------- types ----------
typedef __bf16 bf16x8 __attribute__((ext_vector_type(8)));
typedef float  f32x4  __attribute__((ext_vector_type(4)));
typedef unsigned short us8 __attribute__((ext_vector_type(8)));

__device__ __forceinline__ unsigned short f2bf(float f) {
  unsigned int u = __builtin_bit_cast(unsigned int, f);
  u += 0x7FFFu + ((u >> 16) & 1u);   // round-to-nearest-even
  return (unsigned short)(u >> 16);
}
__device__ __forceinline__ float bf2f(unsigned short h) {
  unsigned int u = ((unsigned int)h) << 16;
  return __builtin_bit_cast(float, u);
}
__device__ __forceinline__ float sigmoid_f(float x) {
  return 1.f / (1.f + __expf(-x));
}
// NaN-safe fast tanh: 1 - 2/(e^{2x}+1)
__device__ __forceinline__ float tanh_f(float x) {
  float e = __expf(2.f * x);
  return 1.f - 2.f / (e + 1.f);
}

// ---------- f32 -> bf16 cast, 8 elems/thread ----------
__global__ void cast_f32_bf16(const float* __restrict__ in,
                              unsigned short* __restrict__ out, long n) {
  long i = ((long)blockIdx.x * blockDim.x + threadIdx.x) * 8;
  if (i >= n) return;
  f32x4 a = *(const f32x4*)(in + i);
  f32x4 b = *(const f32x4*)(in + i + 4);
  us8 o;
  o[0] = f2bf(a[0]); o[1] = f2bf(a[1]); o[2] = f2bf(a[2]); o[3] = f2bf(a[3]);
  o[4] = f2bf(b[0]); o[5] = f2bf(b[1]); o[6] = f2bf(b[2]); o[7] = f2bf(b[3]);
  *(us8*)(out + i) = o;
}

#define GLOAD(gp, lp) __builtin_amdgcn_global_load_lds( \
    (const __attribute__((address_space(1))) unsigned int*)(gp), \
    (__attribute__((address_space(3))) unsigned int*)(lp), 16, 0, 0)

// ---------- Fused GRU cell, counted-vmcnt schedule ----------
// Block: 256 batch-rows x 64 H-cols (x3 gates). 8 waves = 4M x 2C.
// Wave tile 64x32 per gate-acc. K-tiles of 64: t=0..7 over inp/wih (K=512),
// t=8..23 over h/whh (K=1024). LDS double-buffered, XOR-swizzled
// (byte ^= (row&7)<<4), staged via pre-swizzled global source (linear dest).
__global__ __launch_bounds__(512, 2) void fused_gru(
    const unsigned short* __restrict__ inp_b,
    const unsigned short* __restrict__ h_b,
    const unsigned short* __restrict__ wih,
    const unsigned short* __restrict__ whh,
    const float* __restrict__ b_ih,
    const float* __restrict__ b_hh,
    const float* __restrict__ hidden,      // [B,1024] f32
    float* __restrict__ hnew_f32,
    unsigned short* __restrict__ hnew_b)
{
  __shared__ unsigned short lsA[2][256 * 64];      // 2 x 32KB
  __shared__ unsigned short lsW[2][3 * 64 * 64];   // 2 x 24KB (3 gate panels)

  const int tid  = threadIdx.x;
  const int lane = tid & 63;
  const int w    = tid >> 6;
  const int wr   = w >> 1;      // 0..3 (M)
  const int wc   = w & 1;       // 0..1 (C)

  // bijective XCD swizzle (nwg = 1024, %8 == 0)
  const int nwg = gridDim.x * gridDim.y;
  int bid = blockIdx.y * gridDim.x + blockIdx.x;
  int cpx = nwg >> 3;
  int sw  = (bid & 7) * cpx + (bid >> 3);
  const int m0 = (sw / gridDim.x) * 256;
  const int n0 = (sw % gridDim.x) * 64;

  // staging: 7 x 1KB chunks per wave (A:4, W:3); chunk = 8 rows of 128B
  const int sub = lane >> 3;                 // row within chunk (0..7)
  const int cbg = (lane & 7) ^ sub;          // inverse-swizzled col-block

  auto stage = [&](int buf, int t) {
    const unsigned short* Ab; const unsigned short* Wb; int KA, k0;
    if (t < 8) { Ab = inp_b; Wb = wih; KA = 512;  k0 = t * 64; }
    else       { Ab = h_b;   Wb = whh; KA = 1024; k0 = (t - 8) * 64; }
#pragma unroll
    for (int i = 0; i < 4; ++i) {
      int ci  = w * 4 + i;                   // 0..31
      int row = ci * 8 + sub;
      GLOAD(Ab + (size_t)(m0 + row) * KA + k0 + cbg * 8, &lsA[buf][ci * 512]);
    }
#pragma unroll
    for (int i = 0; i < 3; ++i) {
      int ci  = w * 3 + i;                   // 0..23
      int g   = ci >> 3;
      int row = (ci & 7) * 8 + sub;          // row within panel
      GLOAD(Wb + (size_t)(g * 1024 + n0 + row) * KA + k0 + cbg * 8,
            &lsW[buf][ci * 512]);
    }
  };

  f32x4 accR[4][2], accZ[4][2], accNi[4][2], accNh[4][2];
#pragma unroll
  for (int m = 0; m < 4; ++m)
#pragma unroll
    for (int n = 0; n < 2; ++n) {
      accR[m][n]  = f32x4{0.f, 0.f, 0.f, 0.f};
      accZ[m][n]  = f32x4{0.f, 0.f, 0.f, 0.f};
      accNi[m][n] = f32x4{0.f, 0.f, 0.f, 0.f};
      accNh[m][n] = f32x4{0.f, 0.f, 0.f, 0.f};
    }

  const int t4 = lane >> 4;                  // 0..3 (k sub-block)
  const int rA = wr * 64 + (lane & 15);
  const int rW = wc * 32 + (lane & 15);
  const int sx = lane & 7;                   // read-side swizzle XOR

  auto compute = [&](int buf, f32x4 (*accN)[2]) {
#pragma unroll
    for (int ks = 0; ks < 2; ++ks) {
      int scb = (ks * 4 + t4) ^ sx;          // swizzled col-block
      bf16x8 af[4], bfr[3][2];
#pragma unroll
      for (int m = 0; m < 4; ++m)
        af[m] = *(const bf16x8*)&lsA[buf][(rA + m * 16) * 64 + scb * 8];
#pragma unroll
      for (int g = 0; g < 3; ++g)
#pragma unroll
        for (int n = 0; n < 2; ++n)
          bfr[g][n] = *(const bf16x8*)&lsW[buf][g * 4096 + (rW + n * 16) * 64 + scb * 8];
      __builtin_amdgcn_s_setprio(1);
#pragma unroll
      for (int m = 0; m < 4; ++m)
#pragma unroll
        for (int n = 0; n < 2; ++n) {
          accR[m][n] = __builtin_amdgcn_mfma_f32_16x16x32_bf16(af[m], bfr[0][n], accR[m][n], 0, 0, 0);
          accZ[m][n] = __builtin_amdgcn_mfma_f32_16x16x32_bf16(af[m], bfr[1][n], accZ[m][n], 0, 0, 0);
          accN[m][n] = __builtin_amdgcn_mfma_f32_16x16x32_bf16(af[m], bfr[2][n], accN[m][n], 0, 0, 0);
        }
      __builtin_amdgcn_s_setprio(0);
    }
  };

  stage(0, 0);
  int buf = 0;
  for (int t = 0; t < 24; ++t) {
    if (t < 23) {
      stage(buf ^ 1, t + 1);                              // 7 loads in flight
      asm volatile("s_waitcnt vmcnt(7)" ::: "memory");    // wait current tile only
    } else {
      asm volatile("s_waitcnt vmcnt(0)" ::: "memory");
    }
    __builtin_amdgcn_s_barrier();
    if (t < 8) compute(buf, accNi);
    else       compute(buf, accNh);
    __builtin_amdgcn_sched_barrier(0);       // no ds_read sinks past reuse point
    __builtin_amdgcn_s_barrier();
    buf ^= 1;
  }

  // ---- epilogue: gate math + blend ----
  const int colb = n0 + wc * 32 + (lane & 15);
  const int rowb = m0 + wr * 64 + (t4 << 2);
#pragma unroll
  for (int n = 0; n < 2; ++n) {
    int c = colb + n * 16;
    float br  = b_ih[c]        + b_hh[c];
    float bz  = b_ih[1024 + c] + b_hh[1024 + c];
    float bni = b_ih[2048 + c];
    float bnh = b_hh[2048 + c];
#pragma unroll
    for (int m = 0; m < 4; ++m) {
      int row = rowb + m * 16;
#pragma unroll
      for (int r = 0; r < 4; ++r) {
        float rg = sigmoid_f(accR[m][n][r] + br);
        float zg = sigmoid_f(accZ[m][n][r] + bz);
        float ng = tanh_f((accNi[m][n][r] + bni) + rg * (accNh[m][n][r] + bnh));
        float ho = hidden[(size_t)(row + r) * 1024 + c];
        float hv = (1.f - zg) * ng + zg * ho;
        hnew_f32[(size_t)(row + r) * 1024 + c] = hv;
        hnew_b [(size_t)(row + r) * 1024 + c] = f2bf(hv);
      }
    }
  }
}

// ---------- out GEMM: C = tanh(A[M,K] * Bm[N,K]^T + bias), f32 out ----------
__global__ __launch_bounds__(256) void gemm_out(
    const unsigned short* __restrict__ A,
    const unsigned short* __restrict__ Bm,
    float* __restrict__ Cout,
    const float* __restrict__ bias,
    int M, int N, int K)
{
  __shared__ unsigned short lsA[2][128 * 32];
  __shared__ unsigned short lsB[2][128 * 32];

  const int tid  = threadIdx.x;
  const int lane = tid & 63;
  const int wave = tid >> 6;
  const int wr = wave >> 1, wc = wave & 1;
  const int m0 = blockIdx.y * 128;
  const int n0 = blockIdx.x * 128;

  auto stage = [&](int buf, int kt) {
    const int k0 = kt * 32;
#pragma unroll
    for (int it = 0; it < 2; ++it) {
      int li  = it * 256 + tid;
      int row = li >> 2;
      int col = (li & 3) << 3;
      GLOAD(A  + (size_t)(m0 + row) * K + k0 + col, &lsA[buf][li * 8]);
      GLOAD(Bm + (size_t)(n0 + row) * K + k0 + col, &lsB[buf][li * 8]);
    }
  };

  f32x4 acc[4][4];
#pragma unroll
  for (int i = 0; i < 4; ++i)
#pragma unroll
    for (int j = 0; j < 4; ++j) acc[i][j] = f32x4{0.f, 0.f, 0.f, 0.f};

  const int nk = K >> 5;
  stage(0, 0);
  __syncthreads();
  int buf = 0;
  for (int kt = 0; kt < nk; ++kt) {
    if (kt + 1 < nk) stage(buf ^ 1, kt + 1);
    const int kofs = (lane >> 4) << 3;
    const int rA = wr * 64 + (lane & 15);
    const int rB = wc * 64 + (lane & 15);
    bf16x8 af[4], bfr[4];
#pragma unroll
    for (int m = 0; m < 4; ++m)
      af[m] = *(const bf16x8*)&lsA[buf][(rA + m * 16) * 32 + kofs];
#pragma unroll
    for (int n = 0; n < 4; ++n)
      bfr[n] = *(const bf16x8*)&lsB[buf][(rB + n * 16) * 32 + kofs];
#pragma unroll
    for (int m = 0; m < 4; ++m)
#pragma unroll
      for (int n = 0; n < 4; ++n)
        acc[m][n] = __builtin_amdgcn_mfma_f32_16x16x32_bf16(af[m], bfr[n], acc[m][n], 0, 0, 0);
    __syncthreads();
    buf ^= 1;
  }

  const int colb = n0 + wc * 64 + (lane & 15);
  const int rowb = m0 + wr * 64 + ((lane >> 4) << 2);
#pragma unroll
  for (int n = 0; n < 4; ++n) {
    int col = colb + n * 16;
    float bv = bias[col];
#pragma unroll
    for (int m = 0; m < 4; ++m) {
      int row = rowb + m * 16;
#pragma unroll
      for (int r = 0; r < 4; ++r) {
        Cout[(size_t)(row + r) * N + col] = tanh_f(acc[m][n][r] + bv);
      }
    }
  }
}

// ---------- launch ----------
extern "C" void kernel_launch(void* const* d_in, const int* in_sizes, int n_in,
                              void* d_out, int out_size, void* d_ws, size_t ws_size,
                              hipStream_t stream) {
  const int B = 16384, H = 1024, O = 512;
  const float* inp    = (const float*)d_in[0];
  const float* hidden = (const float*)d_in[1];
  const float* w_ih   = (const float*)d_in[2];
  const float* w_hh   = (const float*)d_in[3];
  const float* b_ih   = (const float*)d_in[4];
  const float* b_hh   = (const float*)d_in[5];
  const float* w_out  = (const float*)d_in[6];
  const float* b_out  = (const float*)d_in[7];

  float* out      = (float*)d_out;                     // [B, O] f32
  float* hnew_out = out + (size_t)B * O;               // [1, B, H] f32

  char* ws = (char*)d_ws;
  size_t need = 0;
  auto carve = [&](size_t elems) {
    unsigned short* p = (unsigned short*)(ws + need);
    need += elems * 2;
    return p;
  };
  unsigned short* inp_b  = carve((size_t)B * O);       // 16 MB
  unsigned short* h_b    = carve((size_t)B * H);       // 32 MB
  unsigned short* wih_b  = carve((size_t)3 * H * O);   // 3 MB
  unsigned short* whh_b  = carve((size_t)3 * H * H);   // 6 MB
  unsigned short* wout_b = carve((size_t)O * H);       // 1 MB
  unsigned short* hnew_b = carve((size_t)B * H);       // 32 MB
  if (ws_size < need) return;

  auto cast = [&](const float* src, unsigned short* dst, long n) {
    cast_f32_bf16<<<dim3((unsigned)((n / 8 + 255) / 256)), dim3(256), 0, stream>>>(src, dst, n);
  };
  cast(inp,    inp_b,  (long)B * O);
  cast(hidden, h_b,    (long)B * H);
  cast(w_ih,   wih_b,  (long)3 * H * O);
  cast(w_hh,   whh_b,  (long)3 * H * H);
  cast(w_out,  wout_b, (long)O * H);

  // fused GRU cell -> h_new (f32 into d_out tail, bf16 into ws)
  fused_gru<<<dim3(H / 64, B / 256), dim3(512), 0, stream>>>(
      inp_b, h_b, wih_b, whh_b, b_ih, b_hh, hidden, hnew_out, hnew_b);

  // out = tanh(h_new @ w_out^T + b_out)
  gemm_out<<<dim3(O / 128, B / 128), dim3(256), 0, stream>>>(
      hnew_b, wout_b, out, b_out, B, O, H);
}

// Round 4
// 263.238 us; speedup vs baseline: 4.4478x; 4.4478x over previous
//
#include <hip/hip_runtime.h>

// ---------- types ----------
typedef __bf16 bf16x8 __attribute__((ext_vector_type(8)));
typedef float  f32x4  __attribute__((ext_vector_type(4)));
typedef unsigned short us8 __attribute__((ext_vector_type(8)));

__device__ __forceinline__ unsigned short f2bf(float f) {
  unsigned int u = __builtin_bit_cast(unsigned int, f);
  u += 0x7FFFu + ((u >> 16) & 1u);   // round-to-nearest-even
  return (unsigned short)(u >> 16);
}
__device__ __forceinline__ float bf2f(unsigned short h) {
  unsigned int u = ((unsigned int)h) << 16;
  return __builtin_bit_cast(float, u);
}
__device__ __forceinline__ float sigmoid_f(float x) {
  return 1.f / (1.f + __expf(-x));
}
// NaN-safe fast tanh: 1 - 2/(e^{2x}+1)
__device__ __forceinline__ float tanh_f(float x) {
  float e = __expf(2.f * x);
  return 1.f - 2.f / (e + 1.f);
}

// ---------- f32 -> bf16 cast, 8 elems/thread ----------
__global__ void cast_f32_bf16(const float* __restrict__ in,
                              unsigned short* __restrict__ out, long n) {
  long i = ((long)blockIdx.x * blockDim.x + threadIdx.x) * 8;
  if (i >= n) return;
  f32x4 a = *(const f32x4*)(in + i);
  f32x4 b = *(const f32x4*)(in + i + 4);
  us8 o;
  o[0] = f2bf(a[0]); o[1] = f2bf(a[1]); o[2] = f2bf(a[2]); o[3] = f2bf(a[3]);
  o[4] = f2bf(b[0]); o[5] = f2bf(b[1]); o[6] = f2bf(b[2]); o[7] = f2bf(b[3]);
  *(us8*)(out + i) = o;
}

#define GLOAD(gp, lp) __builtin_amdgcn_global_load_lds( \
    (const __attribute__((address_space(1))) unsigned int*)(gp), \
    (__attribute__((address_space(3))) unsigned int*)(lp), 16, 0, 0)

// ---------- Fused GRU cell (round-2 structure + counted vmcnt) ----------
// Block tile: 128 rows (batch) x 64 cols (H). 4 waves (2M x 2C),
// wave tile 64x32 per gate-accumulator. Four acc sets: r, z, i_n, h_n.
// Phase 0: A=inp_b [B,512],  W=wih,  accNi;  Phase 1: A=h_b [B,1024], W=whh, accNh.
// Per K-tile(32): stage issues 5 global_load_lds/thread; s_waitcnt vmcnt(5)
// keeps the next tile's loads in flight across the barrier (T4).
__global__ __launch_bounds__(256, 2) void fused_gru(
    const unsigned short* __restrict__ inp_b,
    const unsigned short* __restrict__ h_b,
    const unsigned short* __restrict__ wih,
    const unsigned short* __restrict__ whh,
    const float* __restrict__ b_ih,
    const float* __restrict__ b_hh,
    const float* __restrict__ hidden,      // [B,1024] f32
    float* __restrict__ hnew_f32,
    unsigned short* __restrict__ hnew_b)
{
  __shared__ unsigned short lsA[2][128 * 32];      // 2 x 8KB
  __shared__ unsigned short lsW[2][3][64 * 32];    // 2 x 3 x 4KB

  const int tid  = threadIdx.x;
  const int lane = tid & 63;
  const int wave = tid >> 6;
  const int wr = wave >> 1, wc = wave & 1;
  const int m0 = blockIdx.y * 128;   // batch rows
  const int n0 = blockIdx.x * 64;    // H cols

  auto stage = [&](int buf, const unsigned short* Abase, const unsigned short* Wbase,
                   int KA, int kt) {
    const int k0 = kt * 32;
#pragma unroll
    for (int it = 0; it < 2; ++it) {
      int li  = it * 256 + tid;
      int row = li >> 2;
      int col = (li & 3) << 3;
      GLOAD(Abase + (size_t)(m0 + row) * KA + k0 + col, &lsA[buf][li * 8]);
    }
#pragma unroll
    for (int g = 0; g < 3; ++g) {
      int row = tid >> 2;
      int col = (tid & 3) << 3;
      GLOAD(Wbase + (size_t)(g * 1024 + n0 + row) * KA + k0 + col,
            &lsW[buf][g][tid * 8]);
    }
  };

  f32x4 accR[4][2], accZ[4][2], accNi[4][2], accNh[4][2];
#pragma unroll
  for (int m = 0; m < 4; ++m)
#pragma unroll
    for (int n = 0; n < 2; ++n) {
      accR[m][n]  = f32x4{0.f, 0.f, 0.f, 0.f};
      accZ[m][n]  = f32x4{0.f, 0.f, 0.f, 0.f};
      accNi[m][n] = f32x4{0.f, 0.f, 0.f, 0.f};
      accNh[m][n] = f32x4{0.f, 0.f, 0.f, 0.f};
    }

  const int kofs = (lane >> 4) << 3;
  const int rA = wr * 64 + (lane & 15);
  const int rB = wc * 32 + (lane & 15);

  auto compute = [&](int buf, f32x4 (*accN)[2]) {
    bf16x8 af[4], bfr[3][2];
#pragma unroll
    for (int m = 0; m < 4; ++m)
      af[m] = *(const bf16x8*)&lsA[buf][(rA + m * 16) * 32 + kofs];
#pragma unroll
    for (int g = 0; g < 3; ++g)
#pragma unroll
      for (int n = 0; n < 2; ++n)
        bfr[g][n] = *(const bf16x8*)&lsW[buf][g][(rB + n * 16) * 32 + kofs];
#pragma unroll
    for (int m = 0; m < 4; ++m)
#pragma unroll
      for (int n = 0; n < 2; ++n) {
        accR[m][n] = __builtin_amdgcn_mfma_f32_16x16x32_bf16(af[m], bfr[0][n], accR[m][n], 0, 0, 0);
        accZ[m][n] = __builtin_amdgcn_mfma_f32_16x16x32_bf16(af[m], bfr[1][n], accZ[m][n], 0, 0, 0);
        accN[m][n] = __builtin_amdgcn_mfma_f32_16x16x32_bf16(af[m], bfr[2][n], accN[m][n], 0, 0, 0);
      }
  };

  const int nk0 = 512 >> 5;    // 16
  const int nk1 = 1024 >> 5;   // 32

  int buf = 0;
  stage(0, inp_b, wih, 512, 0);
  // phase 0: A=inp, W=wih
  for (int kt = 0; kt < nk0; ++kt) {
    if (kt + 1 < nk0) stage(buf ^ 1, inp_b, wih, 512, kt + 1);
    else              stage(buf ^ 1, h_b,   whh, 1024, 0);
    asm volatile("s_waitcnt vmcnt(5)" ::: "memory");   // tile kt landed; next 5 in flight
    __builtin_amdgcn_s_barrier();
    compute(buf, accNi);
    __builtin_amdgcn_s_barrier();
    buf ^= 1;
  }
  // phase 1: A=h, W=whh
  for (int kt = 0; kt < nk1; ++kt) {
    if (kt + 1 < nk1) {
      stage(buf ^ 1, h_b, whh, 1024, kt + 1);
      asm volatile("s_waitcnt vmcnt(5)" ::: "memory");
    } else {
      asm volatile("s_waitcnt vmcnt(0)" ::: "memory");
    }
    __builtin_amdgcn_s_barrier();
    compute(buf, accNh);
    __builtin_amdgcn_s_barrier();
    buf ^= 1;
  }

  // ---- epilogue: gate math + blend ----
  // C/D layout: col = lane&15, row = (lane>>4)*4 + r
  const int colb = n0 + wc * 32 + (lane & 15);
  const int rowb = m0 + wr * 64 + ((lane >> 4) << 2);
#pragma unroll
  for (int n = 0; n < 2; ++n) {
    int c = colb + n * 16;
    float br  = b_ih[c]        + b_hh[c];
    float bz  = b_ih[1024 + c] + b_hh[1024 + c];
    float bni = b_ih[2048 + c];
    float bnh = b_hh[2048 + c];
#pragma unroll
    for (int m = 0; m < 4; ++m) {
      int row = rowb + m * 16;
#pragma unroll
      for (int r = 0; r < 4; ++r) {
        float rg = sigmoid_f(accR[m][n][r] + br);
        float zg = sigmoid_f(accZ[m][n][r] + bz);
        float ng = tanh_f((accNi[m][n][r] + bni) + rg * (accNh[m][n][r] + bnh));
        float ho = hidden[(size_t)(row + r) * 1024 + c];
        float hv = (1.f - zg) * ng + zg * ho;
        hnew_f32[(size_t)(row + r) * 1024 + c] = hv;
        hnew_b [(size_t)(row + r) * 1024 + c] = f2bf(hv);
      }
    }
  }
}

// ---------- out GEMM: C = tanh(A[M,K] * Bm[N,K]^T + bias), f32 out ----------
__global__ __launch_bounds__(256) void gemm_out(
    const unsigned short* __restrict__ A,
    const unsigned short* __restrict__ Bm,
    float* __restrict__ Cout,
    const float* __restrict__ bias,
    int M, int N, int K)
{
  __shared__ unsigned short lsA[2][128 * 32];
  __shared__ unsigned short lsB[2][128 * 32];

  const int tid  = threadIdx.x;
  const int lane = tid & 63;
  const int wave = tid >> 6;
  const int wr = wave >> 1, wc = wave & 1;
  const int m0 = blockIdx.y * 128;
  const int n0 = blockIdx.x * 128;

  auto stage = [&](int buf, int kt) {
    const int k0 = kt * 32;
#pragma unroll
    for (int it = 0; it < 2; ++it) {
      int li  = it * 256 + tid;
      int row = li >> 2;
      int col = (li & 3) << 3;
      GLOAD(A  + (size_t)(m0 + row) * K + k0 + col, &lsA[buf][li * 8]);
      GLOAD(Bm + (size_t)(n0 + row) * K + k0 + col, &lsB[buf][li * 8]);
    }
  };

  f32x4 acc[4][4];
#pragma unroll
  for (int i = 0; i < 4; ++i)
#pragma unroll
    for (int j = 0; j < 4; ++j) acc[i][j] = f32x4{0.f, 0.f, 0.f, 0.f};

  const int nk = K >> 5;
  stage(0, 0);
  int buf = 0;
  for (int kt = 0; kt < nk; ++kt) {
    if (kt + 1 < nk) {
      stage(buf ^ 1, kt + 1);
      asm volatile("s_waitcnt vmcnt(4)" ::: "memory");
    } else {
      asm volatile("s_waitcnt vmcnt(0)" ::: "memory");
    }
    __builtin_amdgcn_s_barrier();
    const int kofs = (lane >> 4) << 3;
    const int rA = wr * 64 + (lane & 15);
    const int rB = wc * 64 + (lane & 15);
    bf16x8 af[4], bfr[4];
#pragma unroll
    for (int m = 0; m < 4; ++m)
      af[m] = *(const bf16x8*)&lsA[buf][(rA + m * 16) * 32 + kofs];
#pragma unroll
    for (int n = 0; n < 4; ++n)
      bfr[n] = *(const bf16x8*)&lsB[buf][(rB + n * 16) * 32 + kofs];
#pragma unroll
    for (int m = 0; m < 4; ++m)
#pragma unroll
      for (int n = 0; n < 4; ++n)
        acc[m][n] = __builtin_amdgcn_mfma_f32_16x16x32_bf16(af[m], bfr[n], acc[m][n], 0, 0, 0);
    __builtin_amdgcn_s_barrier();
    buf ^= 1;
  }

  const int colb = n0 + wc * 64 + (lane & 15);
  const int rowb = m0 + wr * 64 + ((lane >> 4) << 2);
#pragma unroll
  for (int n = 0; n < 4; ++n) {
    int col = colb + n * 16;
    float bv = bias[col];
#pragma unroll
    for (int m = 0; m < 4; ++m) {
      int row = rowb + m * 16;
#pragma unroll
      for (int r = 0; r < 4; ++r) {
        Cout[(size_t)(row + r) * N + col] = tanh_f(acc[m][n][r] + bv);
      }
    }
  }
}

// ---------- launch ----------
extern "C" void kernel_launch(void* const* d_in, const int* in_sizes, int n_in,
                              void* d_out, int out_size, void* d_ws, size_t ws_size,
                              hipStream_t stream) {
  const int B = 16384, H = 1024, O = 512;
  const float* inp    = (const float*)d_in[0];
  const float* hidden = (const float*)d_in[1];
  const float* w_ih   = (const float*)d_in[2];
  const float* w_hh   = (const float*)d_in[3];
  const float* b_ih   = (const float*)d_in[4];
  const float* b_hh   = (const float*)d_in[5];
  const float* w_out  = (const float*)d_in[6];
  const float* b_out  = (const float*)d_in[7];

  float* out      = (float*)d_out;                     // [B, O] f32
  float* hnew_out = out + (size_t)B * O;               // [1, B, H] f32

  char* ws = (char*)d_ws;
  size_t need = 0;
  auto carve = [&](size_t elems) {
    unsigned short* p = (unsigned short*)(ws + need);
    need += elems * 2;
    return p;
  };
  unsigned short* inp_b  = carve((size_t)B * O);       // 16 MB
  unsigned short* h_b    = carve((size_t)B * H);       // 32 MB
  unsigned short* wih_b  = carve((size_t)3 * H * O);   // 3 MB
  unsigned short* whh_b  = carve((size_t)3 * H * H);   // 6 MB
  unsigned short* wout_b = carve((size_t)O * H);       // 1 MB
  unsigned short* hnew_b = carve((size_t)B * H);       // 32 MB
  if (ws_size < need) return;

  auto cast = [&](const float* src, unsigned short* dst, long n) {
    cast_f32_bf16<<<dim3((unsigned)((n / 8 + 255) / 256)), dim3(256), 0, stream>>>(src, dst, n);
  };
  cast(inp,    inp_b,  (long)B * O);
  cast(hidden, h_b,    (long)B * H);
  cast(w_ih,   wih_b,  (long)3 * H * O);
  cast(w_hh,   whh_b,  (long)3 * H * H);
  cast(w_out,  wout_b, (long)O * H);

  // fused GRU cell -> h_new (f32 into d_out tail, bf16 into ws)
  fused_gru<<<dim3(H / 64, B / 128), dim3(256), 0, stream>>>(
      inp_b, h_b, wih_b, whh_b, b_ih, b_hh, hidden, hnew_out, hnew_b);

  // out = tanh(h_new @ w_out^T + b_out)
  gemm_out<<<dim3(O / 128, B / 128), dim3(256), 0, stream>>>(
      hnew_b, wout_b, out, b_out, B, O, H);
}